// Round 1
// baseline (2474.233 us; speedup 1.0000x reference)
//
#include <hip/hip_runtime.h>
#include <cstdint>
#include <cmath>

// TropicalHashGrid forward: instant-ngp hash-grid encode.
// L=16 levels, F=2 feats, T=19 (HASHMAP=524288), N_MIN=16, N_MAX=2048.
// Levels 0..4 are dense (res 16,23,31,43,59), 5..15 hashed.
// Thread mapping: one thread per (point, level); tid = local_pt*16 + level
// so a wave covers 4 points x 16 levels and the float2 output stores are a
// contiguous 512B/wave stream.

typedef float f32x2 __attribute__((ext_vector_type(2)));

#define NLEVELS 16
#define HASHMAP (1 << 19)
#define HMASK ((uint32_t)(HASHMAP - 1))
#define PRIME_Y 2654435761u
#define PRIME_Z 805459861u

struct HGParams {
    float scale[NLEVELS];
    int   res[NLEVELS];
    int   dense[NLEVELS];
};

__global__ __launch_bounds__(256) void hashgrid_fwd(
    const float* __restrict__ x,
    const float* __restrict__ table,
    float* __restrict__ out,
    HGParams p,
    int npoints)
{
    __shared__ float sx[48];  // 16 points x 3 coords per block
    const int tid = threadIdx.x;
    const int blockPt = blockIdx.x << 4;  // 16 points per 256-thread block

    // Coalesced stage of the block's 16 points into LDS.
    if (tid < 48) {
        int gi = blockPt * 3 + tid;
        sx[tid] = (gi < npoints * 3) ? x[gi] : 0.0f;
    }
    __syncthreads();

    const int pi = tid >> 4;   // local point 0..15
    const int l  = tid & 15;   // level 0..15
    const int n  = blockPt + pi;
    if (n >= npoints) return;

    const float scale = p.scale[l];
    const int   res   = p.res[l];
    const bool  dense = (p.dense[l] != 0);

    // tcnn convention: pos = x*scale + 0.5
    const float px = sx[pi * 3 + 0] * scale + 0.5f;
    const float py = sx[pi * 3 + 1] * scale + 0.5f;
    const float pz = sx[pi * 3 + 2] * scale + 0.5f;
    const float fx = floorf(px), fy = floorf(py), fz = floorf(pz);
    const float rx = px - fx,  ry = py - fy,  rz = pz - fz;
    const int ix = (int)fx, iy = (int)fy, iz = (int)fz;

    const f32x2* __restrict__ tbl =
        (const f32x2*)table + (size_t)l * (size_t)HASHMAP;

    // Corner c: bit2 -> x offset, bit1 -> y, bit0 -> z (meshgrid 'ij' order).
    int flat[8];
    if (dense) {
        const int rm = res - 1;
        const int x0 = min(ix, rm),     x1 = min(ix + 1, rm);
        const int y0 = min(iy, rm),     y1 = min(iy + 1, rm);
        const int z0 = min(iz, rm),     z1 = min(iz + 1, rm);
        const int r2 = res * res;
        const int xs0 = x0, xs1 = x1;              // stride 1 in x
        const int ys0 = y0 * res, ys1 = y1 * res;  // stride res in y
        const int zs0 = z0 * r2,  zs1 = z1 * r2;   // stride res^2 in z
#pragma unroll
        for (int c = 0; c < 8; ++c) {
            const int xv = ((c >> 2) & 1) ? xs1 : xs0;
            const int yv = ((c >> 1) & 1) ? ys1 : ys0;
            const int zv = (c & 1)        ? zs1 : zs0;
            flat[c] = xv + yv + zv;
        }
    } else {
        const uint32_t hx0 = (uint32_t)ix;
        const uint32_t hx1 = (uint32_t)(ix + 1);
        const uint32_t hy0 = (uint32_t)iy * PRIME_Y;
        const uint32_t hy1 = (uint32_t)(iy + 1) * PRIME_Y;
        const uint32_t hz0 = (uint32_t)iz * PRIME_Z;
        const uint32_t hz1 = (uint32_t)(iz + 1) * PRIME_Z;
#pragma unroll
        for (int c = 0; c < 8; ++c) {
            const uint32_t hx = ((c >> 2) & 1) ? hx1 : hx0;
            const uint32_t hy = ((c >> 1) & 1) ? hy1 : hy0;
            const uint32_t hz = (c & 1)        ? hz1 : hz0;
            flat[c] = (int)((hx ^ hy ^ hz) & HMASK);
        }
    }

    // Issue all 8 gathers before any use -> 8 loads in flight per thread.
    f32x2 f[8];
#pragma unroll
    for (int c = 0; c < 8; ++c) f[c] = tbl[flat[c]];

    const float wx[2] = {1.0f - rx, rx};
    const float wy[2] = {1.0f - ry, ry};
    const float wz[2] = {1.0f - rz, rz};

    f32x2 acc;
    acc.x = 0.0f; acc.y = 0.0f;
#pragma unroll
    for (int c = 0; c < 8; ++c) {
        const float w = wx[(c >> 2) & 1] * wy[(c >> 1) & 1] * wz[c & 1];
        acc.x += w * f[c].x;
        acc.y += w * f[c].y;
    }

    // out[n, 2l .. 2l+1]; wave-contiguous float2 stores. Nontemporal: the
    // 256 MiB output stream must not evict the gather tables from L2.
    f32x2* op = (f32x2*)out + (size_t)n * NLEVELS + l;
    __builtin_nontemporal_store(acc, op);
}

extern "C" void kernel_launch(void* const* d_in, const int* in_sizes, int n_in,
                              void* d_out, int out_size, void* d_ws, size_t ws_size,
                              hipStream_t stream) {
    const float* x     = (const float*)d_in[0];
    const float* table = (const float*)d_in[1];
    float* out         = (float*)d_out;
    const int npoints  = in_sizes[0] / 3;

    // Level constants in double, bit-matching the numpy reference:
    // B = 2^(log2(2048/16)/15) = 2^(7/15); scale_l = 16*B^l - 1.
    HGParams p;
    const double B = pow(2.0, 7.0 / 15.0);
    for (int l = 0; l < NLEVELS; ++l) {
        const double s = 16.0 * pow(B, (double)l) - 1.0;
        p.scale[l] = (float)s;
        const int res = (int)ceil(s) + 1;
        p.res[l] = res;
        const long long r3 = (long long)res * res * res;
        p.dense[l] = (r3 <= (long long)HASHMAP) ? 1 : 0;
    }

    const int nblocks = (npoints + 15) / 16;
    hashgrid_fwd<<<nblocks, 256, 0, stream>>>(x, table, out, p, npoints);
}

// Round 2
// 1380.459 us; speedup vs baseline: 1.7923x; 1.7923x over previous
//
#include <hip/hip_runtime.h>
#include <cstdint>
#include <cmath>

// TropicalHashGrid forward, level-major restructure.
// R1 lesson: fused all-levels-per-block mapping thrashes L2 (44 MiB hashed
// tables vs 4 MiB/XCD) -> 7.9 GB L2-miss traffic @ 3.7 TB/s = 2237 us.
// R2: blockIdx.y = level (slowest dispatch dim) so only ~1 level's 4 MiB
// table is hot per XCD L2 at a time; write level-major [L][N][2] scratch
// (coalesced nontemporal), then LDS-tiled transpose -> [N][32].

typedef float f32x2 __attribute__((ext_vector_type(2)));

#define NLEVELS 16
#define HASHMAP (1 << 19)
#define HMASK ((uint32_t)(HASHMAP - 1))
#define PRIME_Y 2654435761u
#define PRIME_Z 805459861u

struct HGParams {
    float scale[NLEVELS];
    int   res[NLEVELS];
    int   dense[NLEVELS];
};

// One block = 256 points x 1 level (level = blockIdx.y).
// dst[l*stride_l + n*stride_n]: scratch path stride_l=N,stride_n=1;
// fallback direct path stride_l=1,stride_n=16.
__global__ __launch_bounds__(256) void hashgrid_level(
    const float* __restrict__ x,
    const float* __restrict__ table,
    f32x2* __restrict__ dst,
    HGParams p,
    int npoints,
    size_t stride_l,
    size_t stride_n)
{
    __shared__ float sx[768];  // 256 points x 3 coords
    const int tid = threadIdx.x;
    const int base = blockIdx.x << 8;
    const int l = blockIdx.y;

    // Coalesced stage of this block's 256 points.
    const int total = npoints * 3;
#pragma unroll
    for (int k = 0; k < 3; ++k) {
        const int li = tid + (k << 8);
        const int gi = base * 3 + li;
        sx[li] = (gi < total) ? x[gi] : 0.0f;
    }
    __syncthreads();

    const int n = base + tid;
    if (n >= npoints) return;

    const float scale = p.scale[l];
    const int   res   = p.res[l];
    const bool  dense = (p.dense[l] != 0);

    const float px = sx[tid * 3 + 0] * scale + 0.5f;
    const float py = sx[tid * 3 + 1] * scale + 0.5f;
    const float pz = sx[tid * 3 + 2] * scale + 0.5f;
    const float fx = floorf(px), fy = floorf(py), fz = floorf(pz);
    const float rx = px - fx,  ry = py - fy,  rz = pz - fz;
    const int ix = (int)fx, iy = (int)fy, iz = (int)fz;

    const f32x2* __restrict__ tbl =
        (const f32x2*)table + (size_t)l * (size_t)HASHMAP;

    // Corner c: bit2 -> x offset, bit1 -> y, bit0 -> z (meshgrid 'ij').
    int flat[8];
    if (dense) {
        const int rm = res - 1;
        const int x0 = min(ix, rm),     x1 = min(ix + 1, rm);
        const int y0 = min(iy, rm),     y1 = min(iy + 1, rm);
        const int z0 = min(iz, rm),     z1 = min(iz + 1, rm);
        const int r2 = res * res;
        const int ys0 = y0 * res, ys1 = y1 * res;
        const int zs0 = z0 * r2,  zs1 = z1 * r2;
#pragma unroll
        for (int c = 0; c < 8; ++c) {
            const int xv = ((c >> 2) & 1) ? x1 : x0;
            const int yv = ((c >> 1) & 1) ? ys1 : ys0;
            const int zv = (c & 1)        ? zs1 : zs0;
            flat[c] = xv + yv + zv;
        }
    } else {
        const uint32_t hx0 = (uint32_t)ix;
        const uint32_t hx1 = (uint32_t)(ix + 1);
        const uint32_t hy0 = (uint32_t)iy * PRIME_Y;
        const uint32_t hy1 = (uint32_t)(iy + 1) * PRIME_Y;
        const uint32_t hz0 = (uint32_t)iz * PRIME_Z;
        const uint32_t hz1 = (uint32_t)(iz + 1) * PRIME_Z;
#pragma unroll
        for (int c = 0; c < 8; ++c) {
            const uint32_t hx = ((c >> 2) & 1) ? hx1 : hx0;
            const uint32_t hy = ((c >> 1) & 1) ? hy1 : hy0;
            const uint32_t hz = (c & 1)        ? hz1 : hz0;
            flat[c] = (int)((hx ^ hy ^ hz) & HMASK);
        }
    }

    // All 8 gathers issued before use -> 8 loads in flight per thread.
    f32x2 f[8];
#pragma unroll
    for (int c = 0; c < 8; ++c) f[c] = tbl[flat[c]];

    const float wx[2] = {1.0f - rx, rx};
    const float wy[2] = {1.0f - ry, ry};
    const float wz[2] = {1.0f - rz, rz};

    f32x2 acc;
    acc.x = 0.0f; acc.y = 0.0f;
#pragma unroll
    for (int c = 0; c < 8; ++c) {
        const float w = wx[(c >> 2) & 1] * wy[(c >> 1) & 1] * wz[c & 1];
        acc.x += w * f[c].x;
        acc.y += w * f[c].y;
    }

    __builtin_nontemporal_store(acc, dst + (size_t)l * stride_l + (size_t)n * stride_n);
}

// Transpose [16][N] f32x2 -> [N][16] f32x2. Block handles 64 points.
__global__ __launch_bounds__(256) void transpose_out(
    const f32x2* __restrict__ ws,
    f32x2* __restrict__ out,
    int npoints)
{
    __shared__ f32x2 tile[NLEVELS][65];  // pad 65: conflict-free column reads
    const int tid = threadIdx.x;
    const int base = blockIdx.x << 6;  // 64 points per block

    // Load: lanes of a wave share level, consecutive points -> 512B contig.
#pragma unroll
    for (int k = 0; k < 4; ++k) {
        const int j = tid + (k << 8);
        const int l = j >> 6;
        const int pp = j & 63;
        const int n = base + pp;
        if (n < npoints)
            tile[l][pp] = __builtin_nontemporal_load(ws + (size_t)l * npoints + n);
    }
    __syncthreads();

    // Store: flat j -> point j>>4, level j&15; fully coalesced 128B rows.
#pragma unroll
    for (int k = 0; k < 4; ++k) {
        const int j = tid + (k << 8);
        const int pp = j >> 4;
        const int l = j & 15;
        const int n = base + pp;
        if (n < npoints)
            __builtin_nontemporal_store(tile[l][pp],
                out + (size_t)n * NLEVELS + l);
    }
}

extern "C" void kernel_launch(void* const* d_in, const int* in_sizes, int n_in,
                              void* d_out, int out_size, void* d_ws, size_t ws_size,
                              hipStream_t stream) {
    const float* x     = (const float*)d_in[0];
    const float* table = (const float*)d_in[1];
    float* out         = (float*)d_out;
    const int npoints  = in_sizes[0] / 3;

    // Level constants in double, bit-matching the numpy reference.
    HGParams p;
    const double B = pow(2.0, 7.0 / 15.0);
    for (int l = 0; l < NLEVELS; ++l) {
        const double s = 16.0 * pow(B, (double)l) - 1.0;
        p.scale[l] = (float)s;
        const int res = (int)ceil(s) + 1;
        p.res[l] = res;
        const long long r3 = (long long)res * res * res;
        p.dense[l] = (r3 <= (long long)HASHMAP) ? 1 : 0;
    }

    const dim3 g1((npoints + 255) / 256, NLEVELS);
    const size_t need = (size_t)npoints * NLEVELS * sizeof(f32x2);

    if (ws_size >= need) {
        // Level-major scratch + transpose (preferred path).
        hashgrid_level<<<g1, 256, 0, stream>>>(
            x, table, (f32x2*)d_ws, p, npoints, (size_t)npoints, (size_t)1);
        const int nb2 = (npoints + 63) / 64;
        transpose_out<<<nb2, 256, 0, stream>>>(
            (const f32x2*)d_ws, (f32x2*)out, npoints);
    } else {
        // Fallback: direct strided writes (still level-local gathers).
        hashgrid_level<<<g1, 256, 0, stream>>>(
            x, table, (f32x2*)out, p, npoints, (size_t)1, (size_t)NLEVELS);
    }
}

// Round 3
// 1123.835 us; speedup vs baseline: 2.2016x; 1.2283x over previous
//
#include <hip/hip_runtime.h>
#include <cstdint>
#include <cmath>

// TropicalHashGrid forward, R3.
// R2 established: level-major dispatch -> gathers are L2-hits, kernel is
// bound at ~2.5 cyc per gather lane-lookup (268M lookups). R3 cuts lookups:
//  - hashed levels: x-corner pair (ix even) shares an aligned float4
//    (hash(ix+1) = hash(ix)^1 when ix even, x-prime=1) -> 8->6 avg lookups
//  - dense levels: overlapping-pair repacked table in ws -> 8->4 lookups
//  - transpose rewritten with float4 both sides (was 1.7 TB/s, want ~5)

typedef float f32x2 __attribute__((ext_vector_type(2)));
typedef float f32x4 __attribute__((ext_vector_type(4)));

#define NLEVELS 16
#define HASHMAP (1 << 19)
#define HMASK ((uint32_t)(HASHMAP - 1))
#define PRIME_Y 2654435761u
#define PRIME_Z 805459861u

struct HGParams {
    float scale[NLEVELS];
    int   res[NLEVELS];
    int   dense[NLEVELS];
    int   dpk_off[NLEVELS];  // float4 offset of repacked dense table, or -1
};

// Overlapping-pair repack of dense tables: dpk[k] = (tbl[k], tbl[k+1]).
// Reading tbl[res^3] is safe: each level owns HASHMAP entries > res^3.
__global__ __launch_bounds__(256) void repack_dense_k(
    const f32x2* __restrict__ table, f32x4* __restrict__ dpk, HGParams p)
{
    const int l = blockIdx.y;
    if (!p.dense[l] || p.dpk_off[l] < 0) return;
    const int res = p.res[l];
    const int res3 = res * res * res;
    const f32x2* __restrict__ src = table + (size_t)l * HASHMAP;
    f32x4* __restrict__ dst = dpk + p.dpk_off[l];
    for (int k = blockIdx.x * 256 + threadIdx.x; k < res3; k += gridDim.x * 256) {
        const f32x2 a = src[k];
        const f32x2 b = src[k + 1];
        f32x4 v; v.x = a.x; v.y = a.y; v.z = b.x; v.w = b.y;
        dst[k] = v;
    }
}

// One block = 256 points x 1 level (level = blockIdx.y, slowest dim -> one
// level's 4 MiB table hot per XCD L2).
// dst[l*stride_l + n*stride_n]: ws path stride_l=N,stride_n=1; direct path
// stride_l=1,stride_n=16.
__global__ __launch_bounds__(256) void hashgrid_level(
    const float* __restrict__ x,
    const float* __restrict__ table,
    const f32x4* __restrict__ dpk,   // repacked dense tables or nullptr
    f32x2* __restrict__ dst,
    HGParams p,
    int npoints,
    size_t stride_l,
    size_t stride_n)
{
    __shared__ float sx[768];
    const int tid = threadIdx.x;
    const int base = blockIdx.x << 8;
    const int l = blockIdx.y;

    const int total = npoints * 3;
#pragma unroll
    for (int k = 0; k < 3; ++k) {
        const int li = tid + (k << 8);
        const int gi = base * 3 + li;
        sx[li] = (gi < total) ? x[gi] : 0.0f;
    }
    __syncthreads();

    const int n = base + tid;
    if (n >= npoints) return;

    const float scale = p.scale[l];
    const int   res   = p.res[l];
    const bool  dense = (p.dense[l] != 0);

    const float px = sx[tid * 3 + 0] * scale + 0.5f;
    const float py = sx[tid * 3 + 1] * scale + 0.5f;
    const float pz = sx[tid * 3 + 2] * scale + 0.5f;
    const float fx = floorf(px), fy = floorf(py), fz = floorf(pz);
    const float rx = px - fx,  ry = py - fy,  rz = pz - fz;
    const int ix = (int)fx, iy = (int)fy, iz = (int)fz;

    const f32x2* __restrict__ tbl =
        (const f32x2*)table + (size_t)l * (size_t)HASHMAP;

    const float wx0 = 1.0f - rx, wx1 = rx;
    const float wy_[2] = {1.0f - ry, ry};
    const float wz_[2] = {1.0f - rz, rz};

    float ax = 0.0f, ay = 0.0f;

    if (dense) {
        const int rm = res - 1;
        const int x0 = min(ix, rm), x1 = min(ix + 1, rm);
        const int y0 = min(iy, rm), y1 = min(iy + 1, rm);
        const int z0 = min(iz, rm), z1 = min(iz + 1, rm);
        const int r2 = res * res;
        const int ys[2] = {y0 * res, y1 * res};
        const int zs[2] = {z0 * r2,  z1 * r2};
        const int d = x1 - x0;  // 0 or 1
        if (dpk && p.dpk_off[l] >= 0) {
            const f32x4* __restrict__ dt = dpk + p.dpk_off[l];
            f32x4 f4[4];
#pragma unroll
            for (int c = 0; c < 4; ++c)
                f4[c] = dt[x0 + ys[(c >> 1) & 1] + zs[c & 1]];
#pragma unroll
            for (int c = 0; c < 4; ++c) {
                const f32x2 c0 = f4[c].xy;
                const f32x2 c1 = d ? f4[c].zw : f4[c].xy;
                const float wyz = wy_[(c >> 1) & 1] * wz_[c & 1];
                ax += wyz * (wx0 * c0.x + wx1 * c1.x);
                ay += wyz * (wx0 * c0.y + wx1 * c1.y);
            }
        } else {
            f32x2 f0[4], f1[4];
#pragma unroll
            for (int c = 0; c < 4; ++c) {
                const int b = ys[(c >> 1) & 1] + zs[c & 1];
                f0[c] = tbl[x0 + b];
                f1[c] = tbl[x1 + b];
            }
#pragma unroll
            for (int c = 0; c < 4; ++c) {
                const float wyz = wy_[(c >> 1) & 1] * wz_[c & 1];
                ax += wyz * (wx0 * f0[c].x + wx1 * f1[c].x);
                ay += wyz * (wx0 * f0[c].y + wx1 * f1[c].y);
            }
        }
    } else {
        const uint32_t ux = (uint32_t)ix;
        const uint32_t hy[2] = {(uint32_t)iy * PRIME_Y, (uint32_t)(iy + 1) * PRIME_Y};
        const uint32_t hz[2] = {(uint32_t)iz * PRIME_Z, (uint32_t)(iz + 1) * PRIME_Z};
        const f32x4* __restrict__ t4 = (const f32x4*)tbl;

        uint32_t H0[4], H1[4];
#pragma unroll
        for (int c = 0; c < 4; ++c) {
            const uint32_t hyz = hy[(c >> 1) & 1] ^ hz[c & 1];
            H0[c] = (ux ^ hyz) & HMASK;
            H1[c] = ((ux + 1u) ^ hyz) & HMASK;
        }
        // Both x-corners live in one aligned float4 when ix is even:
        // H1 = H0 ^ 1. Load the pair-float4 always (covers corner x0 and,
        // for even lanes, corner x1); odd lanes fetch corner x1 separately.
        f32x4 f4[4];
#pragma unroll
        for (int c = 0; c < 4; ++c) f4[c] = t4[H0[c] >> 1];

        f32x2 c1v[4];
        if (ux & 1u) {
#pragma unroll
            for (int c = 0; c < 4; ++c) c1v[c] = tbl[H1[c]];
        } else {
#pragma unroll
            for (int c = 0; c < 4; ++c)
                c1v[c] = (H0[c] & 1u) ? f4[c].xy : f4[c].zw;  // opposite slot
        }
#pragma unroll
        for (int c = 0; c < 4; ++c) {
            const f32x2 c0 = (H0[c] & 1u) ? f4[c].zw : f4[c].xy;
            const float wyz = wy_[(c >> 1) & 1] * wz_[c & 1];
            ax += wyz * (wx0 * c0.x + wx1 * c1v[c].x);
            ay += wyz * (wx0 * c0.y + wx1 * c1v[c].y);
        }
    }

    f32x2 acc; acc.x = ax; acc.y = ay;
    __builtin_nontemporal_store(acc, dst + (size_t)l * stride_l + (size_t)n * stride_n);
}

// Transpose [16][N] f32x2 -> [N][16] f32x2, float4 on both global sides.
// Block handles 128 points. Requires npoints even (guarded at launch).
__global__ __launch_bounds__(256) void transpose_out(
    const f32x4* __restrict__ ws4,
    f32x4* __restrict__ out4,
    int npoints)
{
    __shared__ f32x2 tile[NLEVELS][130];  // stride 130: staggers banks
    const int tid = threadIdx.x;
    const int base = blockIdx.x << 7;    // 128 points per block
    const int np2 = npoints >> 1;        // ws row length in float4

    // Load: wave covers one level, 64 consecutive float4 -> 1 KiB contig.
#pragma unroll
    for (int k = 0; k < 4; ++k) {
        const int flat = tid + (k << 8);
        const int l  = flat >> 6;        // 0..15
        const int pr = flat & 63;        // float4 (point-pair) within tile
        const int gp = (base >> 1) + pr;
        if (gp < np2) {
            const f32x4 v = __builtin_nontemporal_load(ws4 + (size_t)l * np2 + gp);
            tile[l][2 * pr]     = v.xy;
            tile[l][2 * pr + 1] = v.zw;
        }
    }
    __syncthreads();

    // Store: out row per point = 8 float4; fully coalesced.
#pragma unroll
    for (int k = 0; k < 4; ++k) {
        const int flat = tid + (k << 8);
        const int nl = flat >> 3;        // local point 0..127
        const int c  = flat & 7;         // level pair 0..7
        const int nn = base + nl;
        if (nn < npoints) {
            const f32x2 a = tile[2 * c][nl];
            const f32x2 b = tile[2 * c + 1][nl];
            f32x4 v; v.x = a.x; v.y = a.y; v.z = b.x; v.w = b.y;
            __builtin_nontemporal_store(v, out4 + (size_t)nn * 8 + c);
        }
    }
}

extern "C" void kernel_launch(void* const* d_in, const int* in_sizes, int n_in,
                              void* d_out, int out_size, void* d_ws, size_t ws_size,
                              hipStream_t stream) {
    const float* x     = (const float*)d_in[0];
    const float* table = (const float*)d_in[1];
    float* out         = (float*)d_out;
    const int npoints  = in_sizes[0] / 3;

    // Level constants in double, bit-matching the numpy reference.
    HGParams p;
    const double B = pow(2.0, 7.0 / 15.0);
    int dpk_total = 0;   // float4 entries needed for dense repack
    int max_res3 = 0;
    for (int l = 0; l < NLEVELS; ++l) {
        const double s = 16.0 * pow(B, (double)l) - 1.0;
        p.scale[l] = (float)s;
        const int res = (int)ceil(s) + 1;
        p.res[l] = res;
        const long long r3 = (long long)res * res * res;
        p.dense[l] = (r3 <= (long long)HASHMAP) ? 1 : 0;
        if (p.dense[l]) {
            p.dpk_off[l] = dpk_total;
            dpk_total += (int)r3;
            if ((int)r3 > max_res3) max_res3 = (int)r3;
        } else {
            p.dpk_off[l] = -1;
        }
    }

    const size_t need_main = (size_t)npoints * NLEVELS * sizeof(f32x2);
    const size_t need_dpk  = (size_t)dpk_total * sizeof(f32x4);

    const bool ws_main = (ws_size >= need_main) && ((npoints & 1) == 0);
    size_t dpk_byte_off = ws_main ? need_main : 0;
    const bool use_dpk = (ws_size >= dpk_byte_off + need_dpk) && dpk_total > 0;

    f32x4* dpk = use_dpk ? (f32x4*)((char*)d_ws + dpk_byte_off) : nullptr;
    if (use_dpk) {
        const dim3 gr((max_res3 + 255) / 256, NLEVELS);
        repack_dense_k<<<gr, 256, 0, stream>>>((const f32x2*)table, dpk, p);
    }

    const dim3 g1((npoints + 255) / 256, NLEVELS);
    if (ws_main) {
        hashgrid_level<<<g1, 256, 0, stream>>>(
            x, table, dpk, (f32x2*)d_ws, p, npoints, (size_t)npoints, (size_t)1);
        const int nb2 = (npoints + 127) / 128;
        transpose_out<<<nb2, 256, 0, stream>>>(
            (const f32x4*)d_ws, (f32x4*)out, npoints);
    } else {
        hashgrid_level<<<g1, 256, 0, stream>>>(
            x, table, dpk, (f32x2*)out, p, npoints, (size_t)1, (size_t)NLEVELS);
    }
}